// Round 6
// baseline (1137.574 us; speedup 1.0000x reference)
//
#include <hip/hip_runtime.h>

// Instant-NGP style multires hash encoding.
// N=2^20 points, 16 levels, table 2^19 entries x 2 features (float32).
//
// SEMANTICS LEDGER:
//  - q-path: XLA reciprocal-multiply rewrite, constexpr-precomputed table
//    (strict IEEE f32 per op, no contraction). Verified absmax 4.8e-07.
//  - level_idx_w has NO division -> runtime res is bit-identical to
//    compile-time res. corners/wrap/hash/weights precision-robust.
//  - RESOLUTIONS trap: int(16 * 32**(9/15)) == 127, NOT 128.
//
// PERF LEDGER (this session):
//  R3: NT loads/stores -> FETCH 4.0GB, dur 1550us. NT kills LLC residency
//      (~128x line reuse per table line). REVERTED permanently.
//  R4: level-pair ILP: neutral (~950us, VGPR stuck at 32 -> compiler won't
//      hold 16 gathers in flight). Regime: VALUBusy 4.4%, occ 71%,
//      FETCH 3.0GB -> gather-transaction-bound.
//  R5: Morton counting-sort (32^3 bins) + XCD chunk: main kernel 743us
//      (-28%), FETCH 2.06GB, LDS conflicts 4.1M->0.33M. Sort overhead
//      ~248us. CORRECTED MODEL: hash scatters every level's line footprint
//      to ~2-4MB; sorted blocks get L1/L2 locality for res<=203, but each
//      XCD still sweeps ALL 16 levels (~40MB working set vs 4MB L2) ->
//      residual 2.06GB = top-level L2 misses served by LLC @ 2.8TB/s.
//  R6 (this round): LEVEL-PARTITIONED DISPATCH. Grid x8; group g=bid&7
//      (round-robin XCD heuristic) handles levels (g, 15-g) only ->
//      per-XCD working set = 1 big table + 1 small (~4-6MB) -> big-table
//      gathers become home-L2 hits instead of LLC misses. One big table
//      per group = automatic load balance. Sort kept. Math unchanged.
//      Downside bounded: if %8->XCD mapping is wrong, mixing == today.

static constexpr int      kNLevels   = 16;
static constexpr unsigned kTableSize = 1u << 19;
static constexpr unsigned kMask      = kTableSize - 1u;
static constexpr unsigned kP1        = 2654435761u;
static constexpr unsigned kP2        = 805459861u;

static constexpr int kNBins = 32768;   // 32^3 Morton bins

typedef float v4f __attribute__((ext_vector_type(4)));
typedef float v2f __attribute__((ext_vector_type(2)));

// int(16 * 32**(i/15)) with exact Python-double semantics (note 127!)
constexpr int RES_[kNLevels]  = {16, 20, 25, 32, 40, 50, 64, 80,
                                 101, 127, 161, 203, 256, 322, 406, 512};
constexpr int QOFF_[kNLevels] = {0, 16, 36, 61, 93, 133, 183, 247,
                                 327, 428, 555, 716, 919, 1175, 1497, 1903};
static constexpr int kQTot = 2415;  // sum of RES_

// q(c,res) under XLA reciprocal-multiply semantics:
//   r = RN32(1/res); v = RN32(c*r); q = trunc(((v+1)*0.5)*262144)
constexpr unsigned qval_rcp(int c, int res) {
    const float r = 1.0f / (float)res;
    const float v = (float)c * r;
    const float s = ((v + 1.0f) * 0.5f) * 262144.0f;
    return (unsigned)s;
}

struct QTab {
    unsigned v[kQTot];
    constexpr QTab() : v{} {
        int o = 0;
        for (int i = 0; i < kNLevels; ++i) {
            for (int c = 0; c < RES_[i]; ++c) v[o + c] = qval_rcp(c, RES_[i]);
            o += RES_[i];
        }
    }
};
__constant__ QTab QT = QTab();

__constant__ int cRES[kNLevels]  = {16, 20, 25, 32, 40, 50, 64, 80,
                                    101, 127, 161, 203, 256, 322, 406, 512};
__constant__ int cQOFF[kNLevels] = {0, 16, 36, 61, 93, 133, 183, 247,
                                    327, 428, 555, 716, 919, 1175, 1497, 1903};

// ---------------- per-level index+weight (verified math, runtime res) ------
// NO division anywhere -> runtime res gives bit-identical results to the
// compile-time-unrolled version verified through R5.
__device__ __forceinline__ void level_idx_w_rt(
    const int res, const unsigned* __restrict__ qt,
    const float px, const float py, const float pz,
    unsigned* __restrict__ idx, float* __restrict__ w)
{
    const float resf = (float)res;

    const float cxf = px * resf, cyf = py * resf, czf = pz * resf;
    const float fx = floorf(cxf), fy = floorf(cyf), fz = floorf(czf);
    const float lx = cxf - fx, ly = cyf - fy, lz = czf - fz;

    const int ix = (int)fx, iy = (int)fy, iz = (int)fz;
    const int cx0 = ix < 0 ? ix + res : (ix >= res ? ix - res : ix);
    const int cy0 = iy < 0 ? iy + res : (iy >= res ? iy - res : iy);
    const int cz0 = iz < 0 ? iz + res : (iz >= res ? iz - res : iz);
    const int cx1 = (cx0 + 1 == res) ? 0 : cx0 + 1;
    const int cy1 = (cy0 + 1 == res) ? 0 : cy0 + 1;
    const int cz1 = (cz0 + 1 == res) ? 0 : cz0 + 1;

    const unsigned qx0 = qt[cx0], qx1 = qt[cx1];
    const unsigned qy0 = qt[cy0], qy1 = qt[cy1];
    const unsigned qz0 = qt[cz0], qz1 = qt[cz1];

    const unsigned hy0 = qy0 * kP1, hy1 = qy1 * kP1;
    const unsigned hz0 = qz0 * kP2, hz1 = qz1 * kP2;

    const float wx0 = 1.0f - lx, wx1 = lx;
    const float wy0 = 1.0f - ly, wy1 = ly;
    const float wz0 = 1.0f - lz, wz1 = lz;

#pragma unroll
    for (int m = 0; m < 8; ++m) {
        const unsigned h = ((m & 4) ? qx1 : qx0) +
                           ((m & 2) ? hy1 : hy0) +
                           ((m & 1) ? hz1 : hz0);
        idx[m] = h & kMask;
        w[m] = (((m & 4) ? wx1 : wx0) * ((m & 2) ? wy1 : wy0)) *
               ((m & 1) ? wz1 : wz0);
    }
}

// ---------------- Morton binning helpers ----------------------------------
__device__ __forceinline__ unsigned spread5(unsigned x) {
    x &= 0x3ffu;
    x = (x | (x << 16)) & 0x30000FFu;
    x = (x | (x << 8))  & 0x300F00Fu;
    x = (x | (x << 4))  & 0x30C30C3u;
    x = (x | (x << 2))  & 0x9249249u;
    return x;
}

__device__ __forceinline__ unsigned point_bin(const float* __restrict__ x, int n) {
    float px = fminf(fmaxf(x[3 * n + 0], -1.0f), 1.0f);
    float py = fminf(fmaxf(x[3 * n + 1], -1.0f), 1.0f);
    float pz = fminf(fmaxf(x[3 * n + 2], -1.0f), 1.0f);
    int cx = (int)((px + 1.0f) * 16.0f); cx = cx > 31 ? 31 : cx;
    int cy = (int)((py + 1.0f) * 16.0f); cy = cy > 31 ? 31 : cy;
    int cz = (int)((pz + 1.0f) * 16.0f); cz = cz > 31 ? 31 : cz;
    return spread5((unsigned)cx) | (spread5((unsigned)cy) << 1) |
           (spread5((unsigned)cz) << 2);
}

// ---------------- sort pipeline kernels ------------------------------------
__global__ void zero_kernel(unsigned* __restrict__ p, int n) {
    int i = blockIdx.x * 256 + threadIdx.x;
    if (i < n) p[i] = 0u;
}

__global__ void hist_kernel(const float* __restrict__ x,
                            unsigned* __restrict__ counts, int N) {
    int n = blockIdx.x * 256 + threadIdx.x;
    if (n >= N) return;
    atomicAdd(&counts[point_bin(x, n)], 1u);
}

// single-block exclusive scan of 32768 counts -> cursor (= bin start)
__global__ __launch_bounds__(1024) void scan_kernel(
    const unsigned* __restrict__ counts, unsigned* __restrict__ cursor) {
    __shared__ unsigned sh[1024];
    const int t = threadIdx.x;
    unsigned loc[32];
    unsigned s = 0;
#pragma unroll
    for (int j = 0; j < 32; ++j) { loc[j] = s; s += counts[t * 32 + j]; }
    sh[t] = s;
    __syncthreads();
    for (int off = 1; off < 1024; off <<= 1) {
        unsigned v = (t >= off) ? sh[t - off] : 0u;
        __syncthreads();
        sh[t] += v;
        __syncthreads();
    }
    const unsigned base = sh[t] - s;
#pragma unroll
    for (int j = 0; j < 32; ++j) cursor[t * 32 + j] = base + loc[j];
}

__global__ void scatter_kernel(const float* __restrict__ x,
                               unsigned* __restrict__ cursor,
                               unsigned* __restrict__ perm, int N) {
    int n = blockIdx.x * 256 + threadIdx.x;
    if (n >= N) return;
    unsigned pos = atomicAdd(&cursor[point_bin(x, n)], 1u);
    perm[pos] = (unsigned)n;
}

// ---------------- main kernel: level-partitioned, sorted -------------------
// Grid = pb*8. Group g = blockIdx.x & 7 handles levels iA=g, iB=15-g for
// point-block blockIdx.x>>3. Round-robin dispatch (bid%8 -> XCD) keeps all
// group-g blocks on one XCD => its L2 holds that group's tables.
__global__ __launch_bounds__(256, 8) void hashenc_pair_kernel(
    const float* __restrict__ x,
    const float* __restrict__ tables,
    float* __restrict__ out,
    const unsigned* __restrict__ perm,
    int N)
{
    const int g    = blockIdx.x & 7;
    const int pbid = blockIdx.x >> 3;
    const int iA = g, iB = 15 - g;
    const int resA = cRES[iA], resB = cRES[iB];
    const int qoA  = cQOFF[iA], qoB = cQOFF[iB];

    // stage only this pair's q slices (<= 528 entries)
    __shared__ unsigned sq[528];
    const int tot = resA + resB;
    for (int t = threadIdx.x; t < tot; t += 256)
        sq[t] = (t < resA) ? QT.v[qoA + t] : QT.v[qoB + (t - resA)];
    __syncthreads();

    const int gp = pbid * 256 + threadIdx.x;
    if (gp >= N) return;
    const int n = (int)perm[gp];

    float px = x[3 * n + 0];
    float py = x[3 * n + 1];
    float pz = x[3 * n + 2];
    px = fminf(fmaxf(px, -1.0f), 1.0f);
    py = fminf(fmaxf(py, -1.0f), 1.0f);
    pz = fminf(fmaxf(pz, -1.0f), 1.0f);

    unsigned ia[8], ib[8];
    float    wa[8], wb[8];
    level_idx_w_rt(resA, sq,        px, py, pz, ia, wa);
    level_idx_w_rt(resB, sq + resA, px, py, pz, ib, wb);

    const v2f* tA = (const v2f*)tables + (size_t)iA * kTableSize;
    const v2f* tB = (const v2f*)tables + (size_t)iB * kTableSize;

    v2f fa[8], fb[8];
#pragma unroll
    for (int m = 0; m < 8; ++m) fa[m] = tA[ia[m]];
#pragma unroll
    for (int m = 0; m < 8; ++m) fb[m] = tB[ib[m]];

    float a0 = 0.0f, a1 = 0.0f, b0 = 0.0f, b1 = 0.0f;
#pragma unroll
    for (int m = 0; m < 8; ++m) {
        a0 += wa[m] * fa[m].x;
        a1 += wa[m] * fa[m].y;
    }
#pragma unroll
    for (int m = 0; m < 8; ++m) {
        b0 += wb[m] * fb[m].x;
        b1 += wb[m] * fb[m].y;
    }

    // two 8B chunk stores into the point's original output row
    v2f* orow = (v2f*)(out + (size_t)n * (2 * kNLevels));
    v2f va = {a0, a1}; orow[iA] = va;
    v2f vb = {b0, b1}; orow[iB] = vb;
}

// ---------------- fallback: unsorted, all 16 levels (R4-verified path) -----
__global__ __launch_bounds__(256, 6) void hashenc_full_kernel(
    const float* __restrict__ x,
    const float* __restrict__ tables,
    float* __restrict__ out,
    int N)
{
    __shared__ unsigned sq[kQTot];
    for (int t = threadIdx.x; t < kQTot; t += 256) sq[t] = QT.v[t];
    __syncthreads();

    const int n = blockIdx.x * 256 + threadIdx.x;
    if (n >= N) return;

    float px = x[3 * n + 0];
    float py = x[3 * n + 1];
    float pz = x[3 * n + 2];
    px = fminf(fmaxf(px, -1.0f), 1.0f);
    py = fminf(fmaxf(py, -1.0f), 1.0f);
    pz = fminf(fmaxf(pz, -1.0f), 1.0f);

    v4f* op = (v4f*)(out + (size_t)n * (2 * kNLevels));

#pragma unroll
    for (int ip = 0; ip < kNLevels / 2; ++ip) {
        const int iA = 2 * ip, iB = 2 * ip + 1;

        unsigned ia[8], ib[8];
        float    wa[8], wb[8];
        level_idx_w_rt(RES_[iA], sq + QOFF_[iA], px, py, pz, ia, wa);
        level_idx_w_rt(RES_[iB], sq + QOFF_[iB], px, py, pz, ib, wb);

        const v2f* tA = (const v2f*)tables + (size_t)iA * kTableSize;
        const v2f* tB = (const v2f*)tables + (size_t)iB * kTableSize;

        v2f fa[8], fb[8];
#pragma unroll
        for (int m = 0; m < 8; ++m) fa[m] = tA[ia[m]];
#pragma unroll
        for (int m = 0; m < 8; ++m) fb[m] = tB[ib[m]];

        float a0 = 0.0f, a1 = 0.0f, b0 = 0.0f, b1 = 0.0f;
#pragma unroll
        for (int m = 0; m < 8; ++m) {
            a0 += wa[m] * fa[m].x;
            a1 += wa[m] * fa[m].y;
        }
#pragma unroll
        for (int m = 0; m < 8; ++m) {
            b0 += wb[m] * fb[m].x;
            b1 += wb[m] * fb[m].y;
        }

        v4f v = {a0, a1, b0, b1};
        op[ip] = v;
    }
}

extern "C" void kernel_launch(void* const* d_in, const int* in_sizes, int n_in,
                              void* d_out, int out_size, void* d_ws, size_t ws_size,
                              hipStream_t stream) {
    const float* x      = (const float*)d_in[0];
    const float* tables = (const float*)d_in[1];
    float*       out    = (float*)d_out;
    const int N = in_sizes[0] / 3;
    const int pb = (N + 255) / 256;

    const size_t need = ((size_t)2 * kNBins + (size_t)N) * sizeof(unsigned);
    if (d_ws != nullptr && ws_size >= need) {
        unsigned* counts = (unsigned*)d_ws;
        unsigned* cursor = counts + kNBins;
        unsigned* perm   = cursor + kNBins;

        hipLaunchKernelGGL(zero_kernel, dim3((kNBins + 255) / 256), dim3(256),
                           0, stream, counts, kNBins);
        hipLaunchKernelGGL(hist_kernel, dim3(pb), dim3(256), 0, stream,
                           x, counts, N);
        hipLaunchKernelGGL(scan_kernel, dim3(1), dim3(1024), 0, stream,
                           counts, cursor);
        hipLaunchKernelGGL(scatter_kernel, dim3(pb), dim3(256), 0, stream,
                           x, cursor, perm, N);
        hipLaunchKernelGGL(hashenc_pair_kernel, dim3(pb * 8), dim3(256),
                           0, stream, x, tables, out, perm, N);
    } else {
        hipLaunchKernelGGL(hashenc_full_kernel, dim3(pb), dim3(256),
                           0, stream, x, tables, out, N);
    }
}

// Round 7
// 957.452 us; speedup vs baseline: 1.1881x; 1.1881x over previous
//
#include <hip/hip_runtime.h>

// Instant-NGP style multires hash encoding.
// N=2^20 points, 16 levels, table 2^19 entries x 2 features (float32).
//
// SEMANTICS LEDGER:
//  - q-path: XLA reciprocal-multiply rewrite, constexpr-precomputed table
//    (strict IEEE f32 per op, no contraction). Verified absmax 4.8e-07.
//  - level_idx_w_rt has NO division -> bit-identical at runtime res.
//  - RESOLUTIONS trap: int(16 * 32**(9/15)) == 127, NOT 128.
//
// PERF LEDGER (this session):
//  R3: NT loads/stores -> FETCH 4.0GB, 1550us. NT kills LLC residency of
//      tables. REVERTED permanently.
//  R4: level-pair ILP: neutral. VGPR stuck 32 -> compiler batches 8 loads.
//  R5: Morton sort (32^3) + XCD chunk: main 743us, FETCH 2.06GB,
//      sort overhead ~248us. BEST BASE.
//  R6: level-partitioned x8 dispatch: REGRESSED (main 885us). 8B partial
//      row writes x8 XCDs -> WRITE 264->641MB; x/perm read x8. REVERTED.
//  LATENCY MODEL (closes exactly): 22 waves/CU x 8 inflight = 176;
//      523K gathers/CU x ~600cy / 176 = ~740us = measured. => raise MLP.
//  R7 (this round): (a) QUAD-level batching: 32 gathers issued per phase,
//      sched_group_barrier(VMEM_READ,32) clusters them, launch_bounds
//      (256,4) lifts VGPR cap to 128 so all 32 v2f stay live.
//      (b) scatter stages sorted points as float4 {x,y,z,bits(n)} -> main
//      kernel point loads fully coalesced, no perm indirection.
//      Math/order per level byte-identical to R5.

static constexpr int      kNLevels   = 16;
static constexpr unsigned kTableSize = 1u << 19;
static constexpr unsigned kMask      = kTableSize - 1u;
static constexpr unsigned kP1        = 2654435761u;
static constexpr unsigned kP2        = 805459861u;

static constexpr int kNBins = 32768;   // 32^3 Morton bins

typedef float v4f __attribute__((ext_vector_type(4)));
typedef float v2f __attribute__((ext_vector_type(2)));

// int(16 * 32**(i/15)) with exact Python-double semantics (note 127!)
constexpr int RES_[kNLevels]  = {16, 20, 25, 32, 40, 50, 64, 80,
                                 101, 127, 161, 203, 256, 322, 406, 512};
constexpr int QOFF_[kNLevels] = {0, 16, 36, 61, 93, 133, 183, 247,
                                 327, 428, 555, 716, 919, 1175, 1497, 1903};
static constexpr int kQTot = 2415;  // sum of RES_

// q(c,res) under XLA reciprocal-multiply semantics:
//   r = RN32(1/res); v = RN32(c*r); q = trunc(((v+1)*0.5)*262144)
constexpr unsigned qval_rcp(int c, int res) {
    const float r = 1.0f / (float)res;
    const float v = (float)c * r;
    const float s = ((v + 1.0f) * 0.5f) * 262144.0f;
    return (unsigned)s;
}

struct QTab {
    unsigned v[kQTot];
    constexpr QTab() : v{} {
        int o = 0;
        for (int i = 0; i < kNLevels; ++i) {
            for (int c = 0; c < RES_[i]; ++c) v[o + c] = qval_rcp(c, RES_[i]);
            o += RES_[i];
        }
    }
};
__constant__ QTab QT = QTab();

// ---------------- per-level index+weight (verified math) -------------------
__device__ __forceinline__ void level_idx_w_rt(
    const int res, const unsigned* __restrict__ qt,
    const float px, const float py, const float pz,
    unsigned* __restrict__ idx, float* __restrict__ w)
{
    const float resf = (float)res;

    const float cxf = px * resf, cyf = py * resf, czf = pz * resf;
    const float fx = floorf(cxf), fy = floorf(cyf), fz = floorf(czf);
    const float lx = cxf - fx, ly = cyf - fy, lz = czf - fz;

    const int ix = (int)fx, iy = (int)fy, iz = (int)fz;
    const int cx0 = ix < 0 ? ix + res : (ix >= res ? ix - res : ix);
    const int cy0 = iy < 0 ? iy + res : (iy >= res ? iy - res : iy);
    const int cz0 = iz < 0 ? iz + res : (iz >= res ? iz - res : iz);
    const int cx1 = (cx0 + 1 == res) ? 0 : cx0 + 1;
    const int cy1 = (cy0 + 1 == res) ? 0 : cy0 + 1;
    const int cz1 = (cz0 + 1 == res) ? 0 : cz0 + 1;

    const unsigned qx0 = qt[cx0], qx1 = qt[cx1];
    const unsigned qy0 = qt[cy0], qy1 = qt[cy1];
    const unsigned qz0 = qt[cz0], qz1 = qt[cz1];

    const unsigned hy0 = qy0 * kP1, hy1 = qy1 * kP1;
    const unsigned hz0 = qz0 * kP2, hz1 = qz1 * kP2;

    const float wx0 = 1.0f - lx, wx1 = lx;
    const float wy0 = 1.0f - ly, wy1 = ly;
    const float wz0 = 1.0f - lz, wz1 = lz;

#pragma unroll
    for (int m = 0; m < 8; ++m) {
        const unsigned h = ((m & 4) ? qx1 : qx0) +
                           ((m & 2) ? hy1 : hy0) +
                           ((m & 1) ? hz1 : hz0);
        idx[m] = h & kMask;
        w[m] = (((m & 4) ? wx1 : wx0) * ((m & 2) ? wy1 : wy0)) *
               ((m & 1) ? wz1 : wz0);
    }
}

// ---------------- Morton binning helpers ----------------------------------
__device__ __forceinline__ unsigned spread5(unsigned x) {
    x &= 0x3ffu;
    x = (x | (x << 16)) & 0x30000FFu;
    x = (x | (x << 8))  & 0x300F00Fu;
    x = (x | (x << 4))  & 0x30C30C3u;
    x = (x | (x << 2))  & 0x9249249u;
    return x;
}

__device__ __forceinline__ unsigned point_bin(const float* __restrict__ x, int n) {
    float px = fminf(fmaxf(x[3 * n + 0], -1.0f), 1.0f);
    float py = fminf(fmaxf(x[3 * n + 1], -1.0f), 1.0f);
    float pz = fminf(fmaxf(x[3 * n + 2], -1.0f), 1.0f);
    int cx = (int)((px + 1.0f) * 16.0f); cx = cx > 31 ? 31 : cx;
    int cy = (int)((py + 1.0f) * 16.0f); cy = cy > 31 ? 31 : cy;
    int cz = (int)((pz + 1.0f) * 16.0f); cz = cz > 31 ? 31 : cz;
    return spread5((unsigned)cx) | (spread5((unsigned)cy) << 1) |
           (spread5((unsigned)cz) << 2);
}

// ---------------- sort pipeline kernels ------------------------------------
__global__ void zero_kernel(unsigned* __restrict__ p, int n) {
    int i = blockIdx.x * 256 + threadIdx.x;
    if (i < n) p[i] = 0u;
}

__global__ void hist_kernel(const float* __restrict__ x,
                            unsigned* __restrict__ counts, int N) {
    int n = blockIdx.x * 256 + threadIdx.x;
    if (n >= N) return;
    atomicAdd(&counts[point_bin(x, n)], 1u);
}

// single-block exclusive scan of 32768 counts -> cursor (= bin start)
__global__ __launch_bounds__(1024) void scan_kernel(
    const unsigned* __restrict__ counts, unsigned* __restrict__ cursor) {
    __shared__ unsigned sh[1024];
    const int t = threadIdx.x;
    unsigned loc[32];
    unsigned s = 0;
#pragma unroll
    for (int j = 0; j < 32; ++j) { loc[j] = s; s += counts[t * 32 + j]; }
    sh[t] = s;
    __syncthreads();
    for (int off = 1; off < 1024; off <<= 1) {
        unsigned v = (t >= off) ? sh[t - off] : 0u;
        __syncthreads();
        sh[t] += v;
        __syncthreads();
    }
    const unsigned base = sh[t] - s;
#pragma unroll
    for (int j = 0; j < 32; ++j) cursor[t * 32 + j] = base + loc[j];
}

// scatter: stage sorted points as float4 {x, y, z, bits(orig_n)}
__global__ void scatter_kernel(const float* __restrict__ x,
                               unsigned* __restrict__ cursor,
                               v4f* __restrict__ xs, int N) {
    int n = blockIdx.x * 256 + threadIdx.x;
    if (n >= N) return;
    unsigned pos = atomicAdd(&cursor[point_bin(x, n)], 1u);
    v4f v = {x[3 * n + 0], x[3 * n + 1], x[3 * n + 2], __int_as_float(n)};
    xs[pos] = v;
}

// ---------------- main kernel: sorted, quad-level batched ------------------
__global__ __launch_bounds__(256, 4) void hashenc_sorted_kernel(
    const v4f* __restrict__ xs,
    const float* __restrict__ tables,
    float* __restrict__ out,
    int N)
{
    __shared__ unsigned sq[kQTot];
    for (int t = threadIdx.x; t < kQTot; t += 256) sq[t] = QT.v[t];
    __syncthreads();

    // XCD-chunked swizzle: each XCD gets a contiguous Morton range (R5 gain)
    int bid = blockIdx.x;
    const int nblk = gridDim.x;
    if ((nblk & 7) == 0) bid = (bid & 7) * (nblk >> 3) + (bid >> 3);

    const int g = bid * 256 + threadIdx.x;
    if (g >= N) return;

    const v4f p = xs[g];                 // coalesced 16B point load
    const int n = __float_as_int(p.w);   // original row

    float px = fminf(fmaxf(p.x, -1.0f), 1.0f);
    float py = fminf(fmaxf(p.y, -1.0f), 1.0f);
    float pz = fminf(fmaxf(p.z, -1.0f), 1.0f);

    v4f* op = (v4f*)(out + (size_t)n * (2 * kNLevels));

    // 4 levels per phase: 32 independent 8B gathers issued back-to-back.
    // sched_group_barrier(VMEM_READ,32) clusters them; launch_bounds(256,4)
    // lifts the VGPR cap to 128 so all 32 v2f results stay live.
#pragma unroll
    for (int q = 0; q < 4; ++q) {
        unsigned id[4][8];
        float    w[4][8];
#pragma unroll
        for (int j = 0; j < 4; ++j) {
            const int lv = 4 * q + j;
            level_idx_w_rt(RES_[lv], sq + QOFF_[lv], px, py, pz, id[j], w[j]);
        }

        v2f f[4][8];
#pragma unroll
        for (int j = 0; j < 4; ++j) {
            const v2f* tb = (const v2f*)tables + (size_t)(4 * q + j) * kTableSize;
#pragma unroll
            for (int m = 0; m < 8; ++m) f[j][m] = tb[id[j][m]];
        }
        __builtin_amdgcn_sched_group_barrier(0x20 /*VMEM_READ*/, 32, 0);

        // per-level accumulation order identical to verified path
#pragma unroll
        for (int half = 0; half < 2; ++half) {
            v4f v;
#pragma unroll
            for (int j2 = 0; j2 < 2; ++j2) {
                const int j = 2 * half + j2;
                float a0 = 0.0f, a1 = 0.0f;
#pragma unroll
                for (int m = 0; m < 8; ++m) {
                    a0 += w[j][m] * f[j][m].x;
                    a1 += w[j][m] * f[j][m].y;
                }
                v[2 * j2 + 0] = a0;
                v[2 * j2 + 1] = a1;
            }
            op[2 * q + half] = v;
        }
    }
}

// ---------------- fallback: unsorted, all 16 levels (verified path) --------
__global__ __launch_bounds__(256, 6) void hashenc_full_kernel(
    const float* __restrict__ x,
    const float* __restrict__ tables,
    float* __restrict__ out,
    int N)
{
    __shared__ unsigned sq[kQTot];
    for (int t = threadIdx.x; t < kQTot; t += 256) sq[t] = QT.v[t];
    __syncthreads();

    const int n = blockIdx.x * 256 + threadIdx.x;
    if (n >= N) return;

    float px = x[3 * n + 0];
    float py = x[3 * n + 1];
    float pz = x[3 * n + 2];
    px = fminf(fmaxf(px, -1.0f), 1.0f);
    py = fminf(fmaxf(py, -1.0f), 1.0f);
    pz = fminf(fmaxf(pz, -1.0f), 1.0f);

    v4f* op = (v4f*)(out + (size_t)n * (2 * kNLevels));

#pragma unroll
    for (int ip = 0; ip < kNLevels / 2; ++ip) {
        const int iA = 2 * ip, iB = 2 * ip + 1;

        unsigned ia[8], ib[8];
        float    wa[8], wb[8];
        level_idx_w_rt(RES_[iA], sq + QOFF_[iA], px, py, pz, ia, wa);
        level_idx_w_rt(RES_[iB], sq + QOFF_[iB], px, py, pz, ib, wb);

        const v2f* tA = (const v2f*)tables + (size_t)iA * kTableSize;
        const v2f* tB = (const v2f*)tables + (size_t)iB * kTableSize;

        v2f fa[8], fb[8];
#pragma unroll
        for (int m = 0; m < 8; ++m) fa[m] = tA[ia[m]];
#pragma unroll
        for (int m = 0; m < 8; ++m) fb[m] = tB[ib[m]];

        float a0 = 0.0f, a1 = 0.0f, b0 = 0.0f, b1 = 0.0f;
#pragma unroll
        for (int m = 0; m < 8; ++m) {
            a0 += wa[m] * fa[m].x;
            a1 += wa[m] * fa[m].y;
        }
#pragma unroll
        for (int m = 0; m < 8; ++m) {
            b0 += wb[m] * fb[m].x;
            b1 += wb[m] * fb[m].y;
        }

        v4f v = {a0, a1, b0, b1};
        op[ip] = v;
    }
}

extern "C" void kernel_launch(void* const* d_in, const int* in_sizes, int n_in,
                              void* d_out, int out_size, void* d_ws, size_t ws_size,
                              hipStream_t stream) {
    const float* x      = (const float*)d_in[0];
    const float* tables = (const float*)d_in[1];
    float*       out    = (float*)d_out;
    const int N = in_sizes[0] / 3;
    const int pb = (N + 255) / 256;

    const size_t need = (size_t)2 * kNBins * sizeof(unsigned)
                      + (size_t)N * sizeof(v4f);
    if (d_ws != nullptr && ws_size >= need) {
        unsigned* counts = (unsigned*)d_ws;
        unsigned* cursor = counts + kNBins;
        v4f*      xs     = (v4f*)(cursor + kNBins);

        hipLaunchKernelGGL(zero_kernel, dim3((kNBins + 255) / 256), dim3(256),
                           0, stream, counts, kNBins);
        hipLaunchKernelGGL(hist_kernel, dim3(pb), dim3(256), 0, stream,
                           x, counts, N);
        hipLaunchKernelGGL(scan_kernel, dim3(1), dim3(1024), 0, stream,
                           counts, cursor);
        hipLaunchKernelGGL(scatter_kernel, dim3(pb), dim3(256), 0, stream,
                           x, cursor, xs, N);
        hipLaunchKernelGGL(hashenc_sorted_kernel, dim3(pb), dim3(256),
                           0, stream, xs, tables, out, N);
    } else {
        hipLaunchKernelGGL(hashenc_full_kernel, dim3(pb), dim3(256),
                           0, stream, x, tables, out, N);
    }
}